// Round 1
// baseline (835.493 us; speedup 1.0000x reference)
//
#include <hip/hip_runtime.h>
#include <hip/hip_bf16.h>

#define NN 50000
#define NE 1600000
#define DIM 128
#define NU 10000

__global__ void k_degrees(const int* __restrict__ src, const int* __restrict__ dst,
                          int* __restrict__ dout, int* __restrict__ din, int ne) {
    int e = blockIdx.x * blockDim.x + threadIdx.x;
    if (e >= ne) return;
    atomicAdd(&dout[src[e]], 1);
    atomicAdd(&din[dst[e]], 1);
}

__global__ void k_norms(const int* __restrict__ dout, const int* __restrict__ din,
                        float* __restrict__ cs, float* __restrict__ cd, int n) {
    int i = blockIdx.x * blockDim.x + threadIdx.x;
    if (i >= n) return;
    cs[i] = 1.0f / sqrtf(fmaxf((float)dout[i], 1.0f));
    cd[i] = 1.0f / sqrtf(fmaxf((float)din[i], 1.0f));
}

__global__ __launch_bounds__(1024) void k_scan(const int* __restrict__ deg,
                                               int* __restrict__ offs, int n) {
    __shared__ int part[1024];
    int t = threadIdx.x;
    int chunk = (n + 1023) >> 10;
    int b = t * chunk, e = min(b + chunk, n);
    int s = 0;
    for (int i = b; i < e; ++i) s += deg[i];
    part[t] = s;
    __syncthreads();
    for (int off = 1; off < 1024; off <<= 1) {
        int v = (t >= off) ? part[t - off] : 0;
        __syncthreads();
        part[t] += v;
        __syncthreads();
    }
    int base = (t == 0) ? 0 : part[t - 1];
    for (int i = b; i < e; ++i) { offs[i] = base; base += deg[i]; }
}

__global__ void k_scatter(const int* __restrict__ src, const int* __restrict__ dst,
                          const int* __restrict__ offs, int* __restrict__ cursor,
                          int* __restrict__ csc, int ne) {
    int e = blockIdx.x * blockDim.x + threadIdx.x;
    if (e >= ne) return;
    int d = dst[e];
    int pos = offs[d] + atomicAdd(&cursor[d], 1);
    csc[pos] = src[e];
}

// Y[r][:] = (X[r][:] @ W) * cs[r]   ; X:[n,128] W:[128,128]
__global__ __launch_bounds__(256) void k_matmul_cs(const float* __restrict__ X,
                                                   const float* __restrict__ W,
                                                   const float* __restrict__ cs,
                                                   float* __restrict__ Y, int nrows) {
    __shared__ float sW[DIM * DIM];  // 64 KB
    for (int i = threadIdx.x * 4; i < DIM * DIM; i += 256 * 4)
        *(float4*)&sW[i] = *(const float4*)&W[i];
    __syncthreads();
    int rl = threadIdx.x >> 6;           // wave id 0..3 -> row within group
    int c = (threadIdx.x & 63) * 2;      // 2 cols per lane
    for (int base = blockIdx.x * 4; base < nrows; base += gridDim.x * 4) {
        int r = base + rl;
        if (r >= nrows) continue;
        const float* xr = X + (size_t)r * DIM;
        float a0 = 0.f, a1 = 0.f;
#pragma unroll 8
        for (int k = 0; k < DIM; ++k) {
            float x = xr[k];                       // wave-uniform broadcast load
            float2 w = *(const float2*)&sW[k * DIM + c];
            a0 = fmaf(x, w.x, a0);
            a1 = fmaf(x, w.y, a1);
        }
        float s = cs[r];
        *(float2*)&Y[(size_t)r * DIM + c] = make_float2(a0 * s, a1 * s);
    }
}

// out[d][:] = relu(cd[d] * sum_{e in CSC[d]} hs[src_e][:] + bias)
__global__ __launch_bounds__(256) void k_aggregate(const float* __restrict__ hs,
                                                   const int* __restrict__ csc,
                                                   const int* __restrict__ offs,
                                                   const int* __restrict__ din,
                                                   const float* __restrict__ cd,
                                                   const float* __restrict__ bias,
                                                   float* __restrict__ out, int n) {
    int wid = threadIdx.x >> 6;
    int lane = threadIdx.x & 63;
    int d = blockIdx.x * 4 + wid;
    if (d >= n) return;
    int beg = offs[d];
    int end = beg + din[d];
    float a0 = 0.f, a1 = 0.f;
    const float* basep = hs + lane * 2;
    for (int i = beg; i < end; ++i) {
        int s = csc[i];                                  // wave-uniform
        float2 v = *(const float2*)(basep + (size_t)s * DIM);  // coalesced 512B/row
        a0 += v.x; a1 += v.y;
    }
    float c = cd[d];
    float2 b = *(const float2*)&bias[lane * 2];
    float o0 = fmaxf(fmaf(a0, c, b.x), 0.f);
    float o1 = fmaxf(fmaf(a1, c, b.y), 0.f);
    *(float2*)&out[(size_t)d * DIM + lane * 2] = make_float2(o0, o1);
}

// R[u][:] = tanh(h[users[u]] @ Ws1 + bs1) @ Ws2 + bs2
__global__ __launch_bounds__(256) void k_sr_head(const float* __restrict__ h,
                                                 const int* __restrict__ users,
                                                 const float* __restrict__ Ws1,
                                                 const float* __restrict__ bs1,
                                                 const float* __restrict__ Ws2,
                                                 const float* __restrict__ bs2,
                                                 float* __restrict__ R, int nu) {
    __shared__ float sW1[DIM * 64];   // 32 KB
    __shared__ float sW2[64 * 64];    // 16 KB
    __shared__ float sT[4][64];
    for (int i = threadIdx.x * 4; i < DIM * 64; i += 256 * 4)
        *(float4*)&sW1[i] = *(const float4*)&Ws1[i];
    for (int i = threadIdx.x * 4; i < 64 * 64; i += 256 * 4)
        *(float4*)&sW2[i] = *(const float4*)&Ws2[i];
    __syncthreads();
    int ul = threadIdx.x >> 6;   // local user 0..3
    int c = threadIdx.x & 63;
    for (int base = blockIdx.x * 4; base < nu; base += gridDim.x * 4) {
        int u = base + ul;
        float t = 0.f;
        if (u < nu) {
            int node = users[u];
            const float* uh = h + (size_t)node * DIM;
            float acc = bs1[c];
#pragma unroll 8
            for (int k = 0; k < DIM; ++k) acc = fmaf(uh[k], sW1[k * 64 + c], acc);
            t = tanhf(acc);
        }
        sT[ul][c] = t;
        __syncthreads();
        if (u < nu) {
            float acc = bs2[c];
#pragma unroll 8
            for (int k = 0; k < 64; ++k) acc = fmaf(sT[ul][k], sW2[k * 64 + c], acc);
            R[(size_t)u * 64 + c] = acc;
        }
        __syncthreads();
    }
}

extern "C" void kernel_launch(void* const* d_in, const int* in_sizes, int n_in,
                              void* d_out, int out_size, void* d_ws, size_t ws_size,
                              hipStream_t stream) {
    const float* features = (const float*)d_in[0];
    const float* W0  = (const float*)d_in[1];
    const float* b0  = (const float*)d_in[2];
    const float* W1  = (const float*)d_in[3];
    const float* b1  = (const float*)d_in[4];
    const float* Ws1 = (const float*)d_in[5];
    const float* bs1 = (const float*)d_in[6];
    const float* Ws2 = (const float*)d_in[7];
    const float* bs2 = (const float*)d_in[8];
    const int* src   = (const int*)d_in[9];
    const int* dst   = (const int*)d_in[10];
    const int* users = (const int*)d_in[11];

    float* R = (float*)d_out;                         // [10000*64]
    float* H = (float*)d_out + (size_t)NU * 64;       // [50000*128]

    char* ws = (char*)d_ws;
    float* hsA   = (float*)(ws + 0);           // 25,600,000 B
    int*   csc   = (int*)  (ws + 25600000);    //  6,400,000 B
    int*   dout  = (int*)  (ws + 32000000);    //    204,800 B
    int*   din   = (int*)  (ws + 32204800);
    int*   cursor= (int*)  (ws + 32409600);
    float* cs    = (float*)(ws + 32614400);
    float* cd    = (float*)(ws + 32819200);
    int*   offs  = (int*)  (ws + 33024000);    // end ~33.2 MB

    hipMemsetAsync(ws + 32000000, 0, 3 * 204800, stream);  // dout, din, cursor

    k_degrees<<<(NE + 255) / 256, 256, 0, stream>>>(src, dst, dout, din, NE);
    k_norms<<<(NN + 255) / 256, 256, 0, stream>>>(dout, din, cs, cd, NN);
    k_scan<<<1, 1024, 0, stream>>>(din, offs, NN);
    k_scatter<<<(NE + 255) / 256, 256, 0, stream>>>(src, dst, offs, cursor, csc, NE);

    // layer 1: hsA = (features @ W0) * cs ; H = relu(agg * cd + b0)
    k_matmul_cs<<<1024, 256, 0, stream>>>(features, W0, cs, hsA, NN);
    k_aggregate<<<(NN + 3) / 4, 256, 0, stream>>>(hsA, csc, offs, din, cd, b0, H, NN);

    // layer 2: hsA = (H @ W1) * cs ; H = relu(agg * cd + b1)
    k_matmul_cs<<<1024, 256, 0, stream>>>(H, W1, cs, hsA, NN);
    k_aggregate<<<(NN + 3) / 4, 256, 0, stream>>>(hsA, csc, offs, din, cd, b1, H, NN);

    // SR head
    k_sr_head<<<2500, 256, 0, stream>>>(H, users, Ws1, bs1, Ws2, bs2, R, NU);
}

// Round 2
// 530.622 us; speedup vs baseline: 1.5746x; 1.5746x over previous
//
#include <hip/hip_runtime.h>
#include <hip/hip_bf16.h>
#include <hip/hip_fp16.h>

#define NN 50000
#define NE 1600000
#define DIM 128
#define NU 10000

__global__ void k_degrees(const int4* __restrict__ src4, const int4* __restrict__ dst4,
                          int* __restrict__ dout, int* __restrict__ din, int ne4) {
    int e = blockIdx.x * blockDim.x + threadIdx.x;
    if (e >= ne4) return;
    int4 s = src4[e], d = dst4[e];
    atomicAdd(&dout[s.x], 1); atomicAdd(&dout[s.y], 1);
    atomicAdd(&dout[s.z], 1); atomicAdd(&dout[s.w], 1);
    atomicAdd(&din[d.x], 1); atomicAdd(&din[d.y], 1);
    atomicAdd(&din[d.z], 1); atomicAdd(&din[d.w], 1);
}

__global__ void k_norms(const int* __restrict__ dout, const int* __restrict__ din,
                        float* __restrict__ cs, float* __restrict__ cd, int n) {
    int i = blockIdx.x * blockDim.x + threadIdx.x;
    if (i >= n) return;
    cs[i] = 1.0f / sqrtf(fmaxf((float)dout[i], 1.0f));
    cd[i] = 1.0f / sqrtf(fmaxf((float)din[i], 1.0f));
}

__global__ __launch_bounds__(1024) void k_scan(const int* __restrict__ deg,
                                               int* __restrict__ offs, int n) {
    __shared__ int part[1024];
    int t = threadIdx.x;
    int chunk = (n + 1023) >> 10;
    int b = t * chunk, e = min(b + chunk, n);
    int s = 0;
    for (int i = b; i < e; ++i) s += deg[i];
    part[t] = s;
    __syncthreads();
    for (int off = 1; off < 1024; off <<= 1) {
        int v = (t >= off) ? part[t - off] : 0;
        __syncthreads();
        part[t] += v;
        __syncthreads();
    }
    int base = (t == 0) ? 0 : part[t - 1];
    for (int i = b; i < e; ++i) { offs[i] = base; base += deg[i]; }
}

__global__ void k_scatter(const int4* __restrict__ src4, const int4* __restrict__ dst4,
                          const int* __restrict__ offs, int* __restrict__ cursor,
                          int* __restrict__ csc, int ne4) {
    int e = blockIdx.x * blockDim.x + threadIdx.x;
    if (e >= ne4) return;
    int4 s = src4[e], d = dst4[e];
    csc[offs[d.x] + atomicAdd(&cursor[d.x], 1)] = s.x;
    csc[offs[d.y] + atomicAdd(&cursor[d.y], 1)] = s.y;
    csc[offs[d.z] + atomicAdd(&cursor[d.z], 1)] = s.z;
    csc[offs[d.w] + atomicAdd(&cursor[d.w], 1)] = s.w;
}

// Y[r][:] = fp16((X[r][:] @ W) * cs[r]) ; 4 rows per wave, 16 rows per block-iter
__global__ __launch_bounds__(256) void k_matmul_cs(const float* __restrict__ X,
                                                   const float* __restrict__ W,
                                                   const float* __restrict__ cs,
                                                   __half* __restrict__ Y, int nrows) {
    __shared__ float sW[DIM * DIM];   // 64 KB
    __shared__ float sX[16][DIM];     //  8 KB
    for (int i = threadIdx.x * 4; i < DIM * DIM; i += 256 * 4)
        *(float4*)&sW[i] = *(const float4*)&W[i];
    int rl = threadIdx.x >> 6;           // wave id 0..3
    int c = (threadIdx.x & 63) * 2;      // 2 cols per lane
    int ngroups = (nrows + 15) >> 4;
    for (int g = blockIdx.x; g < ngroups; g += gridDim.x) {
        __syncthreads();
        {   // stage 16 rows of X (coalesced float4 x2 per thread)
            int row = threadIdx.x >> 4;
            int col = (threadIdx.x & 15) * 8;
            int rr = min(g * 16 + row, nrows - 1);
            const float* xp = X + (size_t)rr * DIM + col;
            *(float4*)&sX[row][col] = *(const float4*)xp;
            *(float4*)&sX[row][col + 4] = *(const float4*)(xp + 4);
        }
        __syncthreads();
        float acc[4][2] = {};
#pragma unroll 4
        for (int k = 0; k < DIM; ++k) {
            float2 w = *(const float2*)&sW[k * DIM + c];
            float x0 = sX[rl * 4 + 0][k];
            float x1 = sX[rl * 4 + 1][k];
            float x2 = sX[rl * 4 + 2][k];
            float x3 = sX[rl * 4 + 3][k];
            acc[0][0] = fmaf(x0, w.x, acc[0][0]); acc[0][1] = fmaf(x0, w.y, acc[0][1]);
            acc[1][0] = fmaf(x1, w.x, acc[1][0]); acc[1][1] = fmaf(x1, w.y, acc[1][1]);
            acc[2][0] = fmaf(x2, w.x, acc[2][0]); acc[2][1] = fmaf(x2, w.y, acc[2][1]);
            acc[3][0] = fmaf(x3, w.x, acc[3][0]); acc[3][1] = fmaf(x3, w.y, acc[3][1]);
        }
#pragma unroll
        for (int j = 0; j < 4; ++j) {
            int r = g * 16 + rl * 4 + j;
            if (r < nrows) {
                float s = cs[r];
                __half2 hv = __float22half2_rn(make_float2(acc[j][0] * s, acc[j][1] * s));
                *(__half2*)&Y[(size_t)r * DIM + c] = hv;
            }
        }
    }
}

// out[d][:] = relu(cd[d] * sum_{e in CSC[d]} hs[src_e][:] + bias) ; fp16 gather, 4-wide MLP
__global__ __launch_bounds__(256) void k_aggregate(const __half* __restrict__ hs,
                                                   const int* __restrict__ csc,
                                                   const int* __restrict__ offs,
                                                   const int* __restrict__ din,
                                                   const float* __restrict__ cd,
                                                   const float* __restrict__ bias,
                                                   float* __restrict__ out, int n) {
    int wid = threadIdx.x >> 6;
    int lane = threadIdx.x & 63;
    int d = blockIdx.x * 4 + wid;
    if (d >= n) return;
    int beg = offs[d];
    int end = beg + din[d];
    float a0 = 0.f, a1 = 0.f, p0 = 0.f, p1 = 0.f, q0 = 0.f, q1 = 0.f, r0 = 0.f, r1 = 0.f;
    const __half* basep = hs + lane * 2;
    int i = beg;
    for (; i + 4 <= end; i += 4) {
        int s0 = csc[i], s1 = csc[i + 1], s2 = csc[i + 2], s3 = csc[i + 3];
        float2 v0 = __half22float2(*(const __half2*)(basep + (size_t)s0 * DIM));
        float2 v1 = __half22float2(*(const __half2*)(basep + (size_t)s1 * DIM));
        float2 v2 = __half22float2(*(const __half2*)(basep + (size_t)s2 * DIM));
        float2 v3 = __half22float2(*(const __half2*)(basep + (size_t)s3 * DIM));
        a0 += v0.x; a1 += v0.y;
        p0 += v1.x; p1 += v1.y;
        q0 += v2.x; q1 += v2.y;
        r0 += v3.x; r1 += v3.y;
    }
    for (; i < end; ++i) {
        int s = csc[i];
        float2 v = __half22float2(*(const __half2*)(basep + (size_t)s * DIM));
        a0 += v.x; a1 += v.y;
    }
    a0 += p0 + q0 + r0;
    a1 += p1 + q1 + r1;
    float c = cd[d];
    float2 b = *(const float2*)&bias[lane * 2];
    float o0 = fmaxf(fmaf(a0, c, b.x), 0.f);
    float o1 = fmaxf(fmaf(a1, c, b.y), 0.f);
    *(float2*)&out[(size_t)d * DIM + lane * 2] = make_float2(o0, o1);
}

// R[u][:] = tanh(h[users[u]] @ Ws1 + bs1) @ Ws2 + bs2 ; user rows staged in LDS
__global__ __launch_bounds__(256) void k_sr_head(const float* __restrict__ h,
                                                 const int* __restrict__ users,
                                                 const float* __restrict__ Ws1,
                                                 const float* __restrict__ bs1,
                                                 const float* __restrict__ Ws2,
                                                 const float* __restrict__ bs2,
                                                 float* __restrict__ R, int nu) {
    __shared__ float sW1[DIM * 64];   // 32 KB
    __shared__ float sW2[64 * 64];    // 16 KB
    __shared__ float sU[4][DIM];      //  2 KB
    __shared__ float sT[4][64];       //  1 KB
    for (int i = threadIdx.x * 4; i < DIM * 64; i += 256 * 4)
        *(float4*)&sW1[i] = *(const float4*)&Ws1[i];
    for (int i = threadIdx.x * 4; i < 64 * 64; i += 256 * 4)
        *(float4*)&sW2[i] = *(const float4*)&Ws2[i];
    int ul = threadIdx.x >> 6;
    int c = threadIdx.x & 63;
    for (int base = blockIdx.x * 4; base < nu; base += gridDim.x * 4) {
        int u = base + ul;
        __syncthreads();
        if (u < nu) {   // stage this user's h row (coalesced float2 per lane)
            int node = users[u];
            *(float2*)&sU[ul][c * 2] = *(const float2*)&h[(size_t)node * DIM + c * 2];
        }
        __syncthreads();
        float t = 0.f;
        if (u < nu) {
            float acc = bs1[c];
#pragma unroll 8
            for (int k = 0; k < DIM; ++k) acc = fmaf(sU[ul][k], sW1[k * 64 + c], acc);
            t = tanhf(acc);
        }
        sT[ul][c] = t;
        __syncthreads();
        if (u < nu) {
            float acc = bs2[c];
#pragma unroll 8
            for (int k = 0; k < 64; ++k) acc = fmaf(sT[ul][k], sW2[k * 64 + c], acc);
            R[(size_t)u * 64 + c] = acc;
        }
    }
}

extern "C" void kernel_launch(void* const* d_in, const int* in_sizes, int n_in,
                              void* d_out, int out_size, void* d_ws, size_t ws_size,
                              hipStream_t stream) {
    const float* features = (const float*)d_in[0];
    const float* W0  = (const float*)d_in[1];
    const float* b0  = (const float*)d_in[2];
    const float* W1  = (const float*)d_in[3];
    const float* b1  = (const float*)d_in[4];
    const float* Ws1 = (const float*)d_in[5];
    const float* bs1 = (const float*)d_in[6];
    const float* Ws2 = (const float*)d_in[7];
    const float* bs2 = (const float*)d_in[8];
    const int* src   = (const int*)d_in[9];
    const int* dst   = (const int*)d_in[10];
    const int* users = (const int*)d_in[11];

    float* R = (float*)d_out;                         // [10000*64]
    float* H = (float*)d_out + (size_t)NU * 64;       // [50000*128]

    char* ws = (char*)d_ws;
    __half* hsA  = (__half*)(ws + 0);          // 12,800,000 B
    int*   csc   = (int*)  (ws + 12800000);    //  6,400,000 B
    int*   dout  = (int*)  (ws + 19200000);    //    200,000 B
    int*   din   = (int*)  (ws + 19400000);
    int*   cursor= (int*)  (ws + 19600000);
    float* cs    = (float*)(ws + 19800000);
    float* cd    = (float*)(ws + 20000000);
    int*   offs  = (int*)  (ws + 20200000);    // end 20.4 MB

    hipMemsetAsync(ws + 19200000, 0, 3 * 200000, stream);  // dout, din, cursor

    k_degrees<<<(NE / 4 + 255) / 256, 256, 0, stream>>>((const int4*)src, (const int4*)dst,
                                                        dout, din, NE / 4);
    k_norms<<<(NN + 255) / 256, 256, 0, stream>>>(dout, din, cs, cd, NN);
    k_scan<<<1, 1024, 0, stream>>>(din, offs, NN);
    k_scatter<<<(NE / 4 + 255) / 256, 256, 0, stream>>>((const int4*)src, (const int4*)dst,
                                                        offs, cursor, csc, NE / 4);

    // layer 1
    k_matmul_cs<<<1024, 256, 0, stream>>>(features, W0, cs, hsA, NN);
    k_aggregate<<<(NN + 3) / 4, 256, 0, stream>>>(hsA, csc, offs, din, cd, b0, H, NN);

    // layer 2
    k_matmul_cs<<<1024, 256, 0, stream>>>(H, W1, cs, hsA, NN);
    k_aggregate<<<(NN + 3) / 4, 256, 0, stream>>>(hsA, csc, offs, din, cd, b1, H, NN);

    // SR head
    k_sr_head<<<2500, 256, 0, stream>>>(H, users, Ws1, bs1, Ws2, bs2, R, NU);
}

// Round 3
// 425.344 us; speedup vs baseline: 1.9643x; 1.2475x over previous
//
#include <hip/hip_runtime.h>
#include <hip/hip_bf16.h>
#include <hip/hip_fp16.h>

#define NN 50000
#define NE 1600000
#define DIM 128
#define NU 10000
#define NB 64            // histogram/scatter blocks
#define SLICE_W 12500    // NN/4 packed-uint8 words per slice
#define NE4 (NE / 4)
#define CHUNK4 (NE4 / NB)  // 6250 int4 per block

// Per-block packed-uint8 histogram of idx4 chunk -> slices[b][SLICE_W]
__global__ __launch_bounds__(256) void k_hist(const int4* __restrict__ idx4,
                                              unsigned int* __restrict__ slices) {
    __shared__ unsigned int lh[SLICE_W];   // 50 KB
    for (int i = threadIdx.x; i < SLICE_W; i += 256) lh[i] = 0u;
    __syncthreads();
    int b = blockIdx.x;
    int beg = b * CHUNK4, end = beg + CHUNK4;
    for (int i = beg + threadIdx.x; i < end; i += 256) {
        int4 v = idx4[i];
        atomicAdd(&lh[v.x >> 2], 1u << ((v.x & 3) * 8));
        atomicAdd(&lh[v.y >> 2], 1u << ((v.y & 3) * 8));
        atomicAdd(&lh[v.z >> 2], 1u << ((v.z & 3) * 8));
        atomicAdd(&lh[v.w >> 2], 1u << ((v.w & 3) * 8));
    }
    __syncthreads();
    unsigned int* out = slices + (size_t)b * SLICE_W;
    for (int i = threadIdx.x; i < SLICE_W; i += 256) out[i] = lh[i];
}

// Sum 64 slices per node for both directions; emit din, dout, cs, cd
__global__ __launch_bounds__(256) void k_reduce_norms(const unsigned int* __restrict__ histD,
                                                      const unsigned int* __restrict__ histS,
                                                      int* __restrict__ din, int* __restrict__ dout,
                                                      float* __restrict__ cs, float* __restrict__ cd) {
    int wi = blockIdx.x * blockDim.x + threadIdx.x;
    if (wi >= SLICE_W) return;
    unsigned int d0 = 0, d1 = 0, d2 = 0, d3 = 0, s0 = 0, s1 = 0, s2 = 0, s3 = 0;
    for (int b = 0; b < NB; ++b) {
        unsigned int wd = histD[(size_t)b * SLICE_W + wi];
        unsigned int ws = histS[(size_t)b * SLICE_W + wi];
        d0 += wd & 0xFFu; d1 += (wd >> 8) & 0xFFu; d2 += (wd >> 16) & 0xFFu; d3 += wd >> 24;
        s0 += ws & 0xFFu; s1 += (ws >> 8) & 0xFFu; s2 += (ws >> 16) & 0xFFu; s3 += ws >> 24;
    }
    int n = wi * 4;
    *(int4*)&din[n] = make_int4(d0, d1, d2, d3);
    *(int4*)&dout[n] = make_int4(s0, s1, s2, s3);
    float4 vcd, vcs;
    vcd.x = rsqrtf(fmaxf((float)d0, 1.f)); vcd.y = rsqrtf(fmaxf((float)d1, 1.f));
    vcd.z = rsqrtf(fmaxf((float)d2, 1.f)); vcd.w = rsqrtf(fmaxf((float)d3, 1.f));
    vcs.x = rsqrtf(fmaxf((float)s0, 1.f)); vcs.y = rsqrtf(fmaxf((float)s1, 1.f));
    vcs.z = rsqrtf(fmaxf((float)s2, 1.f)); vcs.w = rsqrtf(fmaxf((float)s3, 1.f));
    *(float4*)&cd[n] = vcd;
    *(float4*)&cs[n] = vcs;
}

__global__ __launch_bounds__(1024) void k_scan(const int* __restrict__ deg,
                                               int* __restrict__ offs, int n) {
    __shared__ int part[1024];
    int t = threadIdx.x;
    int chunk = (n + 1023) >> 10;
    int b = t * chunk, e = min(b + chunk, n);
    int s = 0;
    for (int i = b; i < e; ++i) s += deg[i];
    part[t] = s;
    __syncthreads();
    for (int off = 1; off < 1024; off <<= 1) {
        int v = (t >= off) ? part[t - off] : 0;
        __syncthreads();
        part[t] += v;
        __syncthreads();
    }
    int base = (t == 0) ? 0 : part[t - 1];
    for (int i = b; i < e; ++i) { offs[i] = base; base += deg[i]; }
}

// rel16[b][n] = sum over b' < b of histD[b'][n]  (fits uint16: <= deg_in <= ~100)
__global__ __launch_bounds__(256) void k_blockbase(const unsigned int* __restrict__ histD,
                                                   unsigned short* __restrict__ rel16) {
    int n = blockIdx.x * blockDim.x + threadIdx.x;
    if (n >= NN) return;
    int wi = n >> 2, sh = (n & 3) * 8;
    unsigned int run = 0;
    for (int b = 0; b < NB; ++b) {
        rel16[(size_t)b * NN + n] = (unsigned short)run;
        run += (histD[(size_t)b * SLICE_W + wi] >> sh) & 0xFFu;
    }
}

// Atomic-free CSC scatter: local position from LDS packed-byte cursor
__global__ __launch_bounds__(256) void k_scatter2(const int4* __restrict__ src4,
                                                  const int4* __restrict__ dst4,
                                                  const int* __restrict__ offs,
                                                  const unsigned short* __restrict__ rel16,
                                                  int* __restrict__ csc) {
    __shared__ unsigned int lc[SLICE_W];   // 50 KB packed byte cursors
    for (int i = threadIdx.x; i < SLICE_W; i += 256) lc[i] = 0u;
    __syncthreads();
    int b = blockIdx.x;
    const unsigned short* rel = rel16 + (size_t)b * NN;
    int beg = b * CHUNK4, end = beg + CHUNK4;
    for (int i = beg + threadIdx.x; i < end; i += 256) {
        int4 s = src4[i];
        int4 d = dst4[i];
#pragma unroll
        for (int j = 0; j < 4; ++j) {
            int dd = (j == 0) ? d.x : (j == 1) ? d.y : (j == 2) ? d.z : d.w;
            int ss = (j == 0) ? s.x : (j == 1) ? s.y : (j == 2) ? s.z : s.w;
            int sh = (dd & 3) * 8;
            unsigned int old = atomicAdd(&lc[dd >> 2], 1u << sh);
            int local = (old >> sh) & 0xFF;
            csc[offs[dd] + rel[dd] + local] = ss;
        }
    }
}

// Y[r][:] = fp16((X[r][:] @ W) * cs[r]) ; 4 rows per wave, 16 rows per block-iter
__global__ __launch_bounds__(256) void k_matmul_cs(const float* __restrict__ X,
                                                   const float* __restrict__ W,
                                                   const float* __restrict__ cs,
                                                   __half* __restrict__ Y, int nrows) {
    __shared__ float sW[DIM * DIM];   // 64 KB
    __shared__ float sX[16][DIM];     //  8 KB
    for (int i = threadIdx.x * 4; i < DIM * DIM; i += 256 * 4)
        *(float4*)&sW[i] = *(const float4*)&W[i];
    int rl = threadIdx.x >> 6;
    int c = (threadIdx.x & 63) * 2;
    int ngroups = (nrows + 15) >> 4;
    for (int g = blockIdx.x; g < ngroups; g += gridDim.x) {
        __syncthreads();
        {
            int row = threadIdx.x >> 4;
            int col = (threadIdx.x & 15) * 8;
            int rr = min(g * 16 + row, nrows - 1);
            const float* xp = X + (size_t)rr * DIM + col;
            *(float4*)&sX[row][col] = *(const float4*)xp;
            *(float4*)&sX[row][col + 4] = *(const float4*)(xp + 4);
        }
        __syncthreads();
        float acc[4][2] = {};
#pragma unroll 4
        for (int k = 0; k < DIM; ++k) {
            float2 w = *(const float2*)&sW[k * DIM + c];
            float x0 = sX[rl * 4 + 0][k];
            float x1 = sX[rl * 4 + 1][k];
            float x2 = sX[rl * 4 + 2][k];
            float x3 = sX[rl * 4 + 3][k];
            acc[0][0] = fmaf(x0, w.x, acc[0][0]); acc[0][1] = fmaf(x0, w.y, acc[0][1]);
            acc[1][0] = fmaf(x1, w.x, acc[1][0]); acc[1][1] = fmaf(x1, w.y, acc[1][1]);
            acc[2][0] = fmaf(x2, w.x, acc[2][0]); acc[2][1] = fmaf(x2, w.y, acc[2][1]);
            acc[3][0] = fmaf(x3, w.x, acc[3][0]); acc[3][1] = fmaf(x3, w.y, acc[3][1]);
        }
#pragma unroll
        for (int j = 0; j < 4; ++j) {
            int r = g * 16 + rl * 4 + j;
            if (r < nrows) {
                float s = cs[r];
                __half2 hv = __float22half2_rn(make_float2(acc[j][0] * s, acc[j][1] * s));
                *(__half2*)&Y[(size_t)r * DIM + c] = hv;
            }
        }
    }
}

// out[d][:] = relu(cd[d] * sum_{e in CSC[d]} hs[src_e][:] + bias)
__global__ __launch_bounds__(256) void k_aggregate(const __half* __restrict__ hs,
                                                   const int* __restrict__ csc,
                                                   const int* __restrict__ offs,
                                                   const int* __restrict__ din,
                                                   const float* __restrict__ cd,
                                                   const float* __restrict__ bias,
                                                   float* __restrict__ out, int n) {
    int wid = threadIdx.x >> 6;
    int lane = threadIdx.x & 63;
    int d = blockIdx.x * 4 + wid;
    if (d >= n) return;
    int beg = offs[d];
    int end = beg + din[d];
    float a0 = 0.f, a1 = 0.f, p0 = 0.f, p1 = 0.f, q0 = 0.f, q1 = 0.f, r0 = 0.f, r1 = 0.f;
    const __half* basep = hs + lane * 2;
    int i = beg;
    for (; i + 4 <= end; i += 4) {
        int s0 = csc[i], s1 = csc[i + 1], s2 = csc[i + 2], s3 = csc[i + 3];
        float2 v0 = __half22float2(*(const __half2*)(basep + (size_t)s0 * DIM));
        float2 v1 = __half22float2(*(const __half2*)(basep + (size_t)s1 * DIM));
        float2 v2 = __half22float2(*(const __half2*)(basep + (size_t)s2 * DIM));
        float2 v3 = __half22float2(*(const __half2*)(basep + (size_t)s3 * DIM));
        a0 += v0.x; a1 += v0.y;
        p0 += v1.x; p1 += v1.y;
        q0 += v2.x; q1 += v2.y;
        r0 += v3.x; r1 += v3.y;
    }
    for (; i < end; ++i) {
        int s = csc[i];
        float2 v = __half22float2(*(const __half2*)(basep + (size_t)s * DIM));
        a0 += v.x; a1 += v.y;
    }
    a0 += p0 + q0 + r0;
    a1 += p1 + q1 + r1;
    float c = cd[d];
    float2 b = *(const float2*)&bias[lane * 2];
    float o0 = fmaxf(fmaf(a0, c, b.x), 0.f);
    float o1 = fmaxf(fmaf(a1, c, b.y), 0.f);
    *(float2*)&out[(size_t)d * DIM + lane * 2] = make_float2(o0, o1);
}

// R[u][:] = tanh(h[users[u]] @ Ws1 + bs1) @ Ws2 + bs2
__global__ __launch_bounds__(256) void k_sr_head(const float* __restrict__ h,
                                                 const int* __restrict__ users,
                                                 const float* __restrict__ Ws1,
                                                 const float* __restrict__ bs1,
                                                 const float* __restrict__ Ws2,
                                                 const float* __restrict__ bs2,
                                                 float* __restrict__ R, int nu) {
    __shared__ float sW1[DIM * 64];
    __shared__ float sW2[64 * 64];
    __shared__ float sU[4][DIM];
    __shared__ float sT[4][64];
    for (int i = threadIdx.x * 4; i < DIM * 64; i += 256 * 4)
        *(float4*)&sW1[i] = *(const float4*)&Ws1[i];
    for (int i = threadIdx.x * 4; i < 64 * 64; i += 256 * 4)
        *(float4*)&sW2[i] = *(const float4*)&Ws2[i];
    int ul = threadIdx.x >> 6;
    int c = threadIdx.x & 63;
    for (int base = blockIdx.x * 4; base < nu; base += gridDim.x * 4) {
        int u = base + ul;
        __syncthreads();
        if (u < nu) {
            int node = users[u];
            *(float2*)&sU[ul][c * 2] = *(const float2*)&h[(size_t)node * DIM + c * 2];
        }
        __syncthreads();
        float t = 0.f;
        if (u < nu) {
            float acc = bs1[c];
#pragma unroll 8
            for (int k = 0; k < DIM; ++k) acc = fmaf(sU[ul][k], sW1[k * 64 + c], acc);
            t = tanhf(acc);
        }
        sT[ul][c] = t;
        __syncthreads();
        if (u < nu) {
            float acc = bs2[c];
#pragma unroll 8
            for (int k = 0; k < 64; ++k) acc = fmaf(sT[ul][k], sW2[k * 64 + c], acc);
            R[(size_t)u * 64 + c] = acc;
        }
    }
}

extern "C" void kernel_launch(void* const* d_in, const int* in_sizes, int n_in,
                              void* d_out, int out_size, void* d_ws, size_t ws_size,
                              hipStream_t stream) {
    const float* features = (const float*)d_in[0];
    const float* W0  = (const float*)d_in[1];
    const float* b0  = (const float*)d_in[2];
    const float* W1  = (const float*)d_in[3];
    const float* b1  = (const float*)d_in[4];
    const float* Ws1 = (const float*)d_in[5];
    const float* bs1 = (const float*)d_in[6];
    const float* Ws2 = (const float*)d_in[7];
    const float* bs2 = (const float*)d_in[8];
    const int* src   = (const int*)d_in[9];
    const int* dst   = (const int*)d_in[10];
    const int* users = (const int*)d_in[11];

    float* R = (float*)d_out;
    float* H = (float*)d_out + (size_t)NU * 64;

    char* ws = (char*)d_ws;
    __half* hsA  = (__half*)(ws + 0);                    // 12.8 MB
    int* csc     = (int*)(ws + 12800000);                //  6.4 MB
    unsigned int* histD = (unsigned int*)(ws + 19200000);//  3.2 MB (64 x 50000B)
    unsigned int* histS = (unsigned int*)(ws + 22400000);//  3.2 MB
    unsigned short* rel16 = (unsigned short*)(ws + 25600000); // 6.4 MB
    int*   din   = (int*)  (ws + 32000000);
    int*   dout  = (int*)  (ws + 32200000);
    float* cs    = (float*)(ws + 32400000);
    float* cd    = (float*)(ws + 32600000);
    int*   offs  = (int*)  (ws + 32800000);              // end 33.0 MB

    k_hist<<<NB, 256, 0, stream>>>((const int4*)dst, histD);
    k_hist<<<NB, 256, 0, stream>>>((const int4*)src, histS);
    k_reduce_norms<<<(SLICE_W + 255) / 256, 256, 0, stream>>>(histD, histS, din, dout, cs, cd);
    k_scan<<<1, 1024, 0, stream>>>(din, offs, NN);
    k_blockbase<<<(NN + 255) / 256, 256, 0, stream>>>(histD, rel16);
    k_scatter2<<<NB, 256, 0, stream>>>((const int4*)src, (const int4*)dst, offs, rel16, csc);

    // layer 1
    k_matmul_cs<<<1024, 256, 0, stream>>>(features, W0, cs, hsA, NN);
    k_aggregate<<<(NN + 3) / 4, 256, 0, stream>>>(hsA, csc, offs, din, cd, b0, H, NN);

    // layer 2
    k_matmul_cs<<<1024, 256, 0, stream>>>(H, W1, cs, hsA, NN);
    k_aggregate<<<(NN + 3) / 4, 256, 0, stream>>>(hsA, csc, offs, din, cd, b1, H, NN);

    // SR head
    k_sr_head<<<2500, 256, 0, stream>>>(H, users, Ws1, bs1, Ws2, bs2, R, NU);
}

// Round 4
// 354.162 us; speedup vs baseline: 2.3591x; 1.2010x over previous
//
#include <hip/hip_runtime.h>
#include <hip/hip_bf16.h>
#include <hip/hip_fp16.h>

#define NN 50000
#define NE 1600000
#define DIM 128
#define NU 10000
#define NB 64            // histogram/scatter blocks
#define SLICE_W 12500    // NN/4 packed-uint8 words per slice
#define NE4 (NE / 4)
#define CHUNK4 (NE4 / NB)  // 6250 int4 per block
#define NSC 49           // scan blocks: ceil(NN/1024)

// Per-block packed-uint8 histogram of idx4 chunk -> slices[b][SLICE_W]
__global__ __launch_bounds__(256) void k_hist(const int4* __restrict__ idx4,
                                              unsigned int* __restrict__ slices) {
    __shared__ unsigned int lh[SLICE_W];   // 50 KB
    for (int i = threadIdx.x; i < SLICE_W; i += 256) lh[i] = 0u;
    __syncthreads();
    int b = blockIdx.x;
    int beg = b * CHUNK4, end = beg + CHUNK4;
    for (int i = beg + threadIdx.x; i < end; i += 256) {
        int4 v = idx4[i];
        atomicAdd(&lh[v.x >> 2], 1u << ((v.x & 3) * 8));
        atomicAdd(&lh[v.y >> 2], 1u << ((v.y & 3) * 8));
        atomicAdd(&lh[v.z >> 2], 1u << ((v.z & 3) * 8));
        atomicAdd(&lh[v.w >> 2], 1u << ((v.w & 3) * 8));
    }
    __syncthreads();
    unsigned int* out = slices + (size_t)b * SLICE_W;
    for (int i = threadIdx.x; i < SLICE_W; i += 256) out[i] = lh[i];
}

// Sum 64 slices per node; emit din, dout, cs, cd, and per-block degree partial sums
__global__ __launch_bounds__(256) void k_reduce_norms(const unsigned int* __restrict__ histD,
                                                      const unsigned int* __restrict__ histS,
                                                      int* __restrict__ din, int* __restrict__ dout,
                                                      float* __restrict__ cs, float* __restrict__ cd,
                                                      int* __restrict__ partials) {
    __shared__ int red[256];
    int wi = blockIdx.x * blockDim.x + threadIdx.x;
    unsigned int d0 = 0, d1 = 0, d2 = 0, d3 = 0, s0 = 0, s1 = 0, s2 = 0, s3 = 0;
    if (wi < SLICE_W) {
        for (int b = 0; b < NB; ++b) {
            unsigned int wd = histD[(size_t)b * SLICE_W + wi];
            unsigned int ws = histS[(size_t)b * SLICE_W + wi];
            d0 += wd & 0xFFu; d1 += (wd >> 8) & 0xFFu; d2 += (wd >> 16) & 0xFFu; d3 += wd >> 24;
            s0 += ws & 0xFFu; s1 += (ws >> 8) & 0xFFu; s2 += (ws >> 16) & 0xFFu; s3 += ws >> 24;
        }
        int n = wi * 4;
        *(int4*)&din[n] = make_int4(d0, d1, d2, d3);
        *(int4*)&dout[n] = make_int4(s0, s1, s2, s3);
        float4 vcd, vcs;
        vcd.x = rsqrtf(fmaxf((float)d0, 1.f)); vcd.y = rsqrtf(fmaxf((float)d1, 1.f));
        vcd.z = rsqrtf(fmaxf((float)d2, 1.f)); vcd.w = rsqrtf(fmaxf((float)d3, 1.f));
        vcs.x = rsqrtf(fmaxf((float)s0, 1.f)); vcs.y = rsqrtf(fmaxf((float)s1, 1.f));
        vcs.z = rsqrtf(fmaxf((float)s2, 1.f)); vcs.w = rsqrtf(fmaxf((float)s3, 1.f));
        *(float4*)&cd[n] = vcd;
        *(float4*)&cs[n] = vcs;
    }
    red[threadIdx.x] = (int)(d0 + d1 + d2 + d3);
    __syncthreads();
    for (int off = 128; off > 0; off >>= 1) {
        if (threadIdx.x < off) red[threadIdx.x] += red[threadIdx.x + off];
        __syncthreads();
    }
    if (threadIdx.x == 0) partials[blockIdx.x] = red[0];
}

// Exclusive scan of NSC partials (one wave)
__global__ __launch_bounds__(64) void k_scan2(const int* __restrict__ partials,
                                              int* __restrict__ bases) {
    int lane = threadIdx.x;
    int v = (lane < NSC) ? partials[lane] : 0;
    int s = v;
    for (int off = 1; off < 64; off <<= 1) {
        int n = __shfl_up(s, off);
        if (lane >= off) s += n;
    }
    if (lane < NSC) bases[lane] = s - v;   // exclusive
}

// Per-block 1024-node exclusive scan of din + base -> offs
__global__ __launch_bounds__(256) void k_scan3(const int* __restrict__ din,
                                               const int* __restrict__ bases,
                                               int* __restrict__ offs) {
    __shared__ int part[256];
    int t = threadIdx.x;
    int n0 = blockIdx.x * 1024 + t * 4;
    int4 d = make_int4(0, 0, 0, 0);
    if (n0 < NN) d = *(const int4*)&din[n0];
    int tsum = d.x + d.y + d.z + d.w;
    part[t] = tsum;
    __syncthreads();
    for (int off = 1; off < 256; off <<= 1) {
        int v = (t >= off) ? part[t - off] : 0;
        __syncthreads();
        part[t] += v;
        __syncthreads();
    }
    if (n0 < NN) {
        int o = bases[blockIdx.x] + part[t] - tsum;
        *(int4*)&offs[n0] = make_int4(o, o + d.x, o + d.x + d.y, o + d.x + d.y + d.z);
    }
}

// rel16[b][n] = sum over b' < b of histD[b'][n]
__global__ __launch_bounds__(256) void k_blockbase(const unsigned int* __restrict__ histD,
                                                   unsigned short* __restrict__ rel16) {
    int n = blockIdx.x * blockDim.x + threadIdx.x;
    if (n >= NN) return;
    int wi = n >> 2, sh = (n & 3) * 8;
    unsigned int run = 0;
    for (int b = 0; b < NB; ++b) {
        rel16[(size_t)b * NN + n] = (unsigned short)run;
        run += (histD[(size_t)b * SLICE_W + wi] >> sh) & 0xFFu;
    }
}

// Atomic-free CSC scatter: local position from LDS packed-byte cursor
__global__ __launch_bounds__(256) void k_scatter2(const int4* __restrict__ src4,
                                                  const int4* __restrict__ dst4,
                                                  const int* __restrict__ offs,
                                                  const unsigned short* __restrict__ rel16,
                                                  int* __restrict__ csc) {
    __shared__ unsigned int lc[SLICE_W];   // 50 KB packed byte cursors
    for (int i = threadIdx.x; i < SLICE_W; i += 256) lc[i] = 0u;
    __syncthreads();
    int b = blockIdx.x;
    const unsigned short* rel = rel16 + (size_t)b * NN;
    int beg = b * CHUNK4, end = beg + CHUNK4;
    for (int i = beg + threadIdx.x; i < end; i += 256) {
        int4 s = src4[i];
        int4 d = dst4[i];
#pragma unroll
        for (int j = 0; j < 4; ++j) {
            int dd = (j == 0) ? d.x : (j == 1) ? d.y : (j == 2) ? d.z : d.w;
            int ss = (j == 0) ? s.x : (j == 1) ? s.y : (j == 2) ? s.z : s.w;
            int sh = (dd & 3) * 8;
            unsigned int old = atomicAdd(&lc[dd >> 2], 1u << sh);
            int local = (old >> sh) & 0xFF;
            csc[offs[dd] + rel[dd] + local] = ss;
        }
    }
}

// Y[r][:] = fp16((X[r][:] @ W) * cs[r]) ; 4 rows per wave, 16 rows per block-iter
__global__ __launch_bounds__(256) void k_matmul_cs(const float* __restrict__ X,
                                                   const float* __restrict__ W,
                                                   const float* __restrict__ cs,
                                                   __half* __restrict__ Y, int nrows) {
    __shared__ float sW[DIM * DIM];   // 64 KB
    __shared__ float sX[16][DIM];     //  8 KB
    for (int i = threadIdx.x * 4; i < DIM * DIM; i += 256 * 4)
        *(float4*)&sW[i] = *(const float4*)&W[i];
    int rl = threadIdx.x >> 6;
    int c = (threadIdx.x & 63) * 2;
    int ngroups = (nrows + 15) >> 4;
    for (int g = blockIdx.x; g < ngroups; g += gridDim.x) {
        __syncthreads();
        {
            int row = threadIdx.x >> 4;
            int col = (threadIdx.x & 15) * 8;
            int rr = min(g * 16 + row, nrows - 1);
            const float* xp = X + (size_t)rr * DIM + col;
            *(float4*)&sX[row][col] = *(const float4*)xp;
            *(float4*)&sX[row][col + 4] = *(const float4*)(xp + 4);
        }
        __syncthreads();
        float acc[4][2] = {};
#pragma unroll 4
        for (int k = 0; k < DIM; ++k) {
            float2 w = *(const float2*)&sW[k * DIM + c];
            float x0 = sX[rl * 4 + 0][k];
            float x1 = sX[rl * 4 + 1][k];
            float x2 = sX[rl * 4 + 2][k];
            float x3 = sX[rl * 4 + 3][k];
            acc[0][0] = fmaf(x0, w.x, acc[0][0]); acc[0][1] = fmaf(x0, w.y, acc[0][1]);
            acc[1][0] = fmaf(x1, w.x, acc[1][0]); acc[1][1] = fmaf(x1, w.y, acc[1][1]);
            acc[2][0] = fmaf(x2, w.x, acc[2][0]); acc[2][1] = fmaf(x2, w.y, acc[2][1]);
            acc[3][0] = fmaf(x3, w.x, acc[3][0]); acc[3][1] = fmaf(x3, w.y, acc[3][1]);
        }
#pragma unroll
        for (int j = 0; j < 4; ++j) {
            int r = g * 16 + rl * 4 + j;
            if (r < nrows) {
                float s = cs[r];
                __half2 hv = __float22half2_rn(make_float2(acc[j][0] * s, acc[j][1] * s));
                *(__half2*)&Y[(size_t)r * DIM + c] = hv;
            }
        }
    }
}

// out[d][:] = relu(cd[d] * sum_{e in CSC[d]} hs[src_e][:] + bias)
__global__ __launch_bounds__(256) void k_aggregate(const __half* __restrict__ hs,
                                                   const int* __restrict__ csc,
                                                   const int* __restrict__ offs,
                                                   const int* __restrict__ din,
                                                   const float* __restrict__ cd,
                                                   const float* __restrict__ bias,
                                                   float* __restrict__ out, int n) {
    int wid = threadIdx.x >> 6;
    int lane = threadIdx.x & 63;
    int d = blockIdx.x * 4 + wid;
    if (d >= n) return;
    int beg = offs[d];
    int end = beg + din[d];
    float a0 = 0.f, a1 = 0.f, p0 = 0.f, p1 = 0.f, q0 = 0.f, q1 = 0.f, r0 = 0.f, r1 = 0.f;
    const __half* basep = hs + lane * 2;
    int i = beg;
    for (; i + 4 <= end; i += 4) {
        int s0 = csc[i], s1 = csc[i + 1], s2 = csc[i + 2], s3 = csc[i + 3];
        float2 v0 = __half22float2(*(const __half2*)(basep + (size_t)s0 * DIM));
        float2 v1 = __half22float2(*(const __half2*)(basep + (size_t)s1 * DIM));
        float2 v2 = __half22float2(*(const __half2*)(basep + (size_t)s2 * DIM));
        float2 v3 = __half22float2(*(const __half2*)(basep + (size_t)s3 * DIM));
        a0 += v0.x; a1 += v0.y;
        p0 += v1.x; p1 += v1.y;
        q0 += v2.x; q1 += v2.y;
        r0 += v3.x; r1 += v3.y;
    }
    for (; i < end; ++i) {
        int s = csc[i];
        float2 v = __half22float2(*(const __half2*)(basep + (size_t)s * DIM));
        a0 += v.x; a1 += v.y;
    }
    a0 += p0 + q0 + r0;
    a1 += p1 + q1 + r1;
    float c = cd[d];
    float2 b = *(const float2*)&bias[lane * 2];
    float o0 = fmaxf(fmaf(a0, c, b.x), 0.f);
    float o1 = fmaxf(fmaf(a1, c, b.y), 0.f);
    *(float2*)&out[(size_t)d * DIM + lane * 2] = make_float2(o0, o1);
}

// R[u][:] = tanh(h[users[u]] @ Ws1 + bs1) @ Ws2 + bs2
__global__ __launch_bounds__(256) void k_sr_head(const float* __restrict__ h,
                                                 const int* __restrict__ users,
                                                 const float* __restrict__ Ws1,
                                                 const float* __restrict__ bs1,
                                                 const float* __restrict__ Ws2,
                                                 const float* __restrict__ bs2,
                                                 float* __restrict__ R, int nu) {
    __shared__ float sW1[DIM * 64];
    __shared__ float sW2[64 * 64];
    __shared__ float sU[4][DIM];
    __shared__ float sT[4][64];
    for (int i = threadIdx.x * 4; i < DIM * 64; i += 256 * 4)
        *(float4*)&sW1[i] = *(const float4*)&Ws1[i];
    for (int i = threadIdx.x * 4; i < 64 * 64; i += 256 * 4)
        *(float4*)&sW2[i] = *(const float4*)&Ws2[i];
    int ul = threadIdx.x >> 6;
    int c = threadIdx.x & 63;
    for (int base = blockIdx.x * 4; base < nu; base += gridDim.x * 4) {
        int u = base + ul;
        __syncthreads();
        if (u < nu) {
            int node = users[u];
            *(float2*)&sU[ul][c * 2] = *(const float2*)&h[(size_t)node * DIM + c * 2];
        }
        __syncthreads();
        float t = 0.f;
        if (u < nu) {
            float acc = bs1[c];
#pragma unroll 8
            for (int k = 0; k < DIM; ++k) acc = fmaf(sU[ul][k], sW1[k * 64 + c], acc);
            t = tanhf(acc);
        }
        sT[ul][c] = t;
        __syncthreads();
        if (u < nu) {
            float acc = bs2[c];
#pragma unroll 8
            for (int k = 0; k < 64; ++k) acc = fmaf(sT[ul][k], sW2[k * 64 + c], acc);
            R[(size_t)u * 64 + c] = acc;
        }
    }
}

extern "C" void kernel_launch(void* const* d_in, const int* in_sizes, int n_in,
                              void* d_out, int out_size, void* d_ws, size_t ws_size,
                              hipStream_t stream) {
    const float* features = (const float*)d_in[0];
    const float* W0  = (const float*)d_in[1];
    const float* b0  = (const float*)d_in[2];
    const float* W1  = (const float*)d_in[3];
    const float* b1  = (const float*)d_in[4];
    const float* Ws1 = (const float*)d_in[5];
    const float* bs1 = (const float*)d_in[6];
    const float* Ws2 = (const float*)d_in[7];
    const float* bs2 = (const float*)d_in[8];
    const int* src   = (const int*)d_in[9];
    const int* dst   = (const int*)d_in[10];
    const int* users = (const int*)d_in[11];

    float* R = (float*)d_out;
    float* H = (float*)d_out + (size_t)NU * 64;

    char* ws = (char*)d_ws;
    __half* hsA  = (__half*)(ws + 0);                    // 12.8 MB
    int* csc     = (int*)(ws + 12800000);                //  6.4 MB
    unsigned int* histD = (unsigned int*)(ws + 19200000);//  3.2 MB
    unsigned int* histS = (unsigned int*)(ws + 22400000);//  3.2 MB
    unsigned short* rel16 = (unsigned short*)(ws + 25600000); // 6.4 MB
    int*   din   = (int*)  (ws + 32000000);
    int*   dout  = (int*)  (ws + 32200000);
    float* cs    = (float*)(ws + 32400000);
    float* cd    = (float*)(ws + 32600000);
    int*   offs  = (int*)  (ws + 32800000);              // 200 KB
    int*   partials = (int*)(ws + 33000000);             // 49 ints
    int*   bases    = (int*)(ws + 33001024);             // 49 ints

    k_hist<<<NB, 256, 0, stream>>>((const int4*)dst, histD);
    k_hist<<<NB, 256, 0, stream>>>((const int4*)src, histS);
    k_reduce_norms<<<NSC, 256, 0, stream>>>(histD, histS, din, dout, cs, cd, partials);
    k_scan2<<<1, 64, 0, stream>>>(partials, bases);
    k_scan3<<<NSC, 256, 0, stream>>>(din, bases, offs);
    k_blockbase<<<(NN + 255) / 256, 256, 0, stream>>>(histD, rel16);
    k_scatter2<<<NB, 256, 0, stream>>>((const int4*)src, (const int4*)dst, offs, rel16, csc);

    // layer 1
    k_matmul_cs<<<1024, 256, 0, stream>>>(features, W0, cs, hsA, NN);
    k_aggregate<<<(NN + 3) / 4, 256, 0, stream>>>(hsA, csc, offs, din, cd, b0, H, NN);

    // layer 2
    k_matmul_cs<<<1024, 256, 0, stream>>>(H, W1, cs, hsA, NN);
    k_aggregate<<<(NN + 3) / 4, 256, 0, stream>>>(hsA, csc, offs, din, cd, b1, H, NN);

    // SR head
    k_sr_head<<<2500, 256, 0, stream>>>(H, users, Ws1, bs1, Ws2, bs2, R, NU);
}